// Round 3
// baseline (439.947 us; speedup 1.0000x reference)
//
#include <hip/hip_runtime.h>

typedef __attribute__((ext_vector_type(8))) short short8;
typedef __attribute__((ext_vector_type(4))) float floatx4;

__device__ __forceinline__ unsigned short f2bf(float f) {
    unsigned u = __float_as_uint(f);
    unsigned r = (u + 0x7fffu + ((u >> 16) & 1u)) >> 16;
    return (unsigned short)r;
}

__device__ __forceinline__ short8 cvt8(const float* p) {
    floatx4 a = *(const floatx4*)p;
    floatx4 b = *(const floatx4*)(p + 4);
    short8 v;
    v[0] = (short)f2bf(a[0]); v[1] = (short)f2bf(a[1]);
    v[2] = (short)f2bf(a[2]); v[3] = (short)f2bf(a[3]);
    v[4] = (short)f2bf(b[0]); v[5] = (short)f2bf(b[1]);
    v[6] = (short)f2bf(b[2]); v[7] = (short)f2bf(b[3]);
    return v;
}

// =============== fused sweep (float4): rowpartY (32 partials) + colsum atomics
// grid (64 c-blocks of 16, 8 r-blocks of 128), 256 thr
__global__ __launch_bounds__(256) void sweep_kernel(const float* __restrict__ in,
        float* __restrict__ rowpartY, float* __restrict__ colsum) {
    int t = threadIdx.x;
    int kq = t & 15;            // k = kq*4 .. kq*4+3
    int rgl = (t >> 4) & 3;     // row phase within wave
    int w = t >> 6;             // wave 0..3
    int rg = t >> 4;            // row phase 0..15
    int c0 = blockIdx.x * 16;
    int r0 = blockIdx.y * 128;
    const float* base = in + ((size_t)(r0 + rg) << 16) + (size_t)c0 * 64 + kq * 4;

    floatx4 rowacc[16];
    #pragma unroll
    for (int c = 0; c < 16; ++c) rowacc[c] = (floatx4){0.f, 0.f, 0.f, 0.f};

    #pragma unroll 2
    for (int i = 0; i < 8; ++i) {
        const float* p = base + ((size_t)i << 20);   // 16 rows * 65536 floats
        floatx4 cv = (floatx4){0.f, 0.f, 0.f, 0.f};
        #pragma unroll
        for (int c = 0; c < 16; ++c) {
            floatx4 v = *(const floatx4*)(p + c * 64);
            rowacc[c] += v;
            cv += v;
        }
        size_t cb = (size_t)(r0 + rg + 16 * i) * 64 + kq * 4;
        atomicAdd(&colsum[cb + 0], cv[0]);
        atomicAdd(&colsum[cb + 1], cv[1]);
        atomicAdd(&colsum[cb + 2], cv[2]);
        atomicAdd(&colsum[cb + 3], cv[3]);
    }

    // reduce row partials over the 4 in-wave phases; lanes 0..15 hold result
    #pragma unroll
    for (int c = 0; c < 16; ++c) {
        floatx4 v = rowacc[c];
        #pragma unroll
        for (int m = 16; m <= 32; m <<= 1) {
            v[0] += __shfl_xor(v[0], m);
            v[1] += __shfl_xor(v[1], m);
            v[2] += __shfl_xor(v[2], m);
            v[3] += __shfl_xor(v[3], m);
        }
        if (rgl == 0)
            *(floatx4*)&rowpartY[(size_t)(blockIdx.y * 4 + w) * 65536
                                 + (size_t)(c0 + c) * 64 + kq * 4] = v;
    }
}

// =============== row_pool/col_pool finalize (32 partials)
__global__ __launch_bounds__(256) void rowfin_kernel(const float* __restrict__ rowpartY,
        const float* __restrict__ colsum, float* __restrict__ row_pool,
        float* __restrict__ col_pool) {
    int j = blockIdx.x * 256 + threadIdx.x;
    float s = 0.f;
    #pragma unroll
    for (int y = 0; y < 32; ++y) s += rowpartY[(size_t)y * 65536 + j];
    row_pool[j] = s * (1.f / 1024.f);
    col_pool[j] = colsum[j] * (1.f / 1024.f);
}

// =============== allpart: partial sums of colsum over r  (64 blocks x 16 r)
__global__ __launch_bounds__(256) void allpart_kernel(const float* __restrict__ colsum,
        float* __restrict__ allpart) {
    int t = threadIdx.x, k = t & 63, rl = t >> 6;
    int b = blockIdx.x;
    float s = 0.f;
    #pragma unroll
    for (int u = 0; u < 4; ++u)
        s += colsum[(size_t)(b * 16 + rl + 4 * u) * 64 + k];
    __shared__ float red[4][64];
    red[rl][k] = s;
    __syncthreads();
    if (t < 64)
        allpart[b * 64 + t] = red[0][t] + red[1][t] + red[2][t] + red[3][t];
}

// =============== diag extraction + partials (256 blocks x 4 i)
__global__ __launch_bounds__(256) void diag_kernel(const float* __restrict__ in,
        float* __restrict__ diagbuf, float* __restrict__ diagpart) {
    int t = threadIdx.x, k = t & 63, il = t >> 6;
    int i = blockIdx.x * 4 + il;
    float v = in[(size_t)i * 1025 * 64 + k];
    diagbuf[i * 64 + k] = v;
    __shared__ float red[4][64];
    red[il][k] = v;
    __syncthreads();
    if (t < 64)
        diagpart[blockIdx.x * 64 + t] = red[0][t] + red[1][t] + red[2][t] + red[3][t];
}

// =============== final tiny reduce: all_sum, diag_sum
__global__ __launch_bounds__(256) void finB_kernel(const float* __restrict__ allpart,
        const float* __restrict__ diagpart, float* __restrict__ all_sum,
        float* __restrict__ diag_sum) {
    int t = threadIdx.x, k = t & 63, rg = t >> 6;
    float sa = 0.f, sd = 0.f;
    for (int b = rg; b < 64; b += 4) sa += allpart[b * 64 + k];
    for (int b = rg; b < 256; b += 4) sd += diagpart[b * 64 + k];
    __shared__ float red[2][4][64];
    red[0][rg][k] = sa;
    red[1][rg][k] = sd;
    __syncthreads();
    if (t < 64) {
        all_sum[t]  = red[0][0][t] + red[0][1][t] + red[0][2][t] + red[0][3][t];
        diag_sum[t] = red[1][0][t] + red[1][1][t] + red[1][2][t] + red[1][3][t];
    }
}

// =============== W0/W1 transposed -> bf16 bits
__global__ __launch_bounds__(256) void wconv_kernel(const float* __restrict__ wts,
        unsigned short* __restrict__ w0t, unsigned short* __restrict__ w1t) {
    int idx = blockIdx.x * 256 + threadIdx.x;
    int n = idx >> 6, k = idx & 63;
    w0t[idx] = f2bf(wts[k * 64 + n]);
    w1t[idx] = f2bf(wts[4096 + k * 64 + n]);
}

// =============== A[c], B[r], Dg[i] tables (fp32)
__global__ __launch_bounds__(64) void abd_kernel(const float* __restrict__ W,
        const float* __restrict__ col_pool, const float* __restrict__ row_pool,
        const float* __restrict__ diagbuf, const float* __restrict__ all_sum,
        const float* __restrict__ diag_sum,
        float* __restrict__ Ab, float* __restrict__ Bb, float* __restrict__ Dgb) {
    __shared__ float rp[64], cp[64], dv[64], ap[64], dp[64];
    int i = blockIdx.x, o = threadIdx.x;
    rp[o] = row_pool[i * 64 + o];
    cp[o] = col_pool[i * 64 + o];
    dv[o] = diagbuf[i * 64 + o];
    ap[o] = all_sum[o] * (1.f / 1048576.f);
    dp[o] = diag_sum[o] * (1.f / 1024.f);
    __syncthreads();
    float aA = 0.f, aB = 0.f, aD = 0.f;
    #pragma unroll 4
    for (int k = 0; k < 64; ++k) {
        int ko = k * 64 + o;
        aA += rp[k] * W[3 * 4096 + ko] + cp[k] * W[6 * 4096 + ko]
            + dv[k] * W[13 * 4096 + ko] + ap[k] * W[7 * 4096 + ko]
            + dp[k] * W[12 * 4096 + ko];
        aB += rp[k] * W[4 * 4096 + ko] + cp[k] * W[5 * 4096 + ko]
            + dv[k] * W[14 * 4096 + ko];
        aD += dv[k] * W[2 * 4096 + ko] + rp[k] * W[10 * 4096 + ko]
            + cp[k] * W[11 * 4096 + ko] + dp[k] * W[8 * 4096 + ko]
            + ap[k] * W[9 * 4096 + ko];
    }
    Ab[i * 64 + o] = aA;
    Bb[i * 64 + o] = aB;
    Dgb[i * 64 + o] = aD;
}

// =============== main paired-tile kernel: 2080 blocks x 512 thr
__global__ __launch_bounds__(512) void main_kernel(const float* __restrict__ in,
        const unsigned short* __restrict__ w0t, const unsigned short* __restrict__ w1t,
        const float* __restrict__ Ab, const float* __restrict__ Bb,
        const float* __restrict__ Dgb, float* __restrict__ out) {
    __shared__ short lds[32768];          // 2 tiles * 256 rows * 64 bf16 (swizzled)

    int t = threadIdx.x;
    int lane = t & 63, w = t >> 6;        // 8 waves
    int lrow = lane & 15, lhi = lane >> 4;

    // triangular decode
    int p = blockIdx.x;
    float fb = (129.0f - sqrtf(129.0f * 129.0f - 8.0f * (float)p)) * 0.5f;
    int bi = (int)fb;
    while (bi > 0 && bi * (129 - bi) / 2 > p) --bi;
    while ((bi + 1) * (129 - (bi + 1)) / 2 <= p) ++bi;
    int bj = bi + (p - bi * (129 - bi) / 2);
    int r0 = bi * 16, c0 = bj * 16;

    // W fragments (register-resident)
    short8 bw0[2][4], bw1[2][4];
    #pragma unroll
    for (int kg = 0; kg < 2; ++kg)
        #pragma unroll
        for (int nt = 0; nt < 4; ++nt) {
            int off = (nt * 16 + lrow) * 64 + kg * 32 + lhi * 8;
            bw0[kg][nt] = *(const short8*)(w0t + off);
            bw1[kg][nt] = *(const short8*)(w1t + off);
        }

    // stage both tiles: thread t -> (sj, sg), i = 4q + (t>>7)
    int sj = (t & 127) >> 3;
    int sg = t & 7;
    int shalf = t >> 7;                   // 0..3
    #pragma unroll
    for (int sel = 0; sel < 2; ++sel) {
        int R = sel ? c0 : r0;
        int C = sel ? r0 : c0;
        #pragma unroll
        for (int q = 0; q < 4; ++q) {
            int i = 4 * q + shalf;
            const float* src = in + (((size_t)(R + i) << 10) + (C + sj)) * 64 + sg * 8;
            short8 v = cvt8(src);
            int row = i * 16 + sj;
            int wg = sg ^ ((row ^ (row >> 4)) & 7);
            *(short8*)(lds + sel * 16384 + row * 64 + wg * 8) = v;
        }
    }
    __syncthreads();

    // compute: wave w does I = 2w, 2w+1 of each out-tile
    #pragma unroll
    for (int sel = 0; sel < 2; ++sel) {
        if (sel == 1 && bi == bj) continue;   // diagonal pair: both tiles identical
        int selb = sel * 16384;
        int othb = (sel ^ 1) * 16384;
        int rbase = sel ? c0 : r0;
        int cbase = sel ? r0 : c0;
        #pragma unroll
        for (int mf = 0; mf < 2; ++mf) {
            int I = w * 2 + mf;
            int mrow = I * 16 + lrow;
            int swzm = (mrow ^ (mrow >> 4)) & 7;
            int trow = lrow * 16 + I;
            int swzt = (trow ^ (trow >> 4)) & 7;
            short8 ad[2], at2[2];
            #pragma unroll
            for (int kg = 0; kg < 2; ++kg) {
                ad[kg]  = *(const short8*)(lds + selb + mrow * 64 + ((kg * 4 + lhi) ^ swzm) * 8);
                at2[kg] = *(const short8*)(lds + othb + trow * 64 + ((kg * 4 + lhi) ^ swzt) * 8);
            }
            floatx4 acc[4];
            #pragma unroll
            for (int nt = 0; nt < 4; ++nt) acc[nt] = (floatx4){0.f, 0.f, 0.f, 0.f};
            #pragma unroll
            for (int nt = 0; nt < 4; ++nt) {
                acc[nt] = __builtin_amdgcn_mfma_f32_16x16x32_bf16(ad[0],  bw0[0][nt], acc[nt], 0, 0, 0);
                acc[nt] = __builtin_amdgcn_mfma_f32_16x16x32_bf16(ad[1],  bw0[1][nt], acc[nt], 0, 0, 0);
                acc[nt] = __builtin_amdgcn_mfma_f32_16x16x32_bf16(at2[0], bw1[0][nt], acc[nt], 0, 0, 0);
                acc[nt] = __builtin_amdgcn_mfma_f32_16x16x32_bf16(at2[1], bw1[1][nt], acc[nt], 0, 0, 0);
            }
            int ridx = rbase + I;
            float br[4];
            #pragma unroll
            for (int nt = 0; nt < 4; ++nt) br[nt] = Bb[ridx * 64 + nt * 16 + lrow];
            #pragma unroll
            for (int jj = 0; jj < 4; ++jj) {
                int j = lhi * 4 + jj;
                int cidx = cbase + j;
                size_t s = ((size_t)ridx << 10) + cidx;
                bool isd = (ridx == cidx);
                #pragma unroll
                for (int nt = 0; nt < 4; ++nt) {
                    int n = nt * 16 + lrow;
                    float v = acc[nt][jj] + Ab[cidx * 64 + n] + br[nt];
                    if (isd) v += Dgb[ridx * 64 + n];
                    out[s * 64 + n] = v;
                }
            }
        }
    }
}

extern "C" void kernel_launch(void* const* d_in, const int* in_sizes, int n_in,
                              void* d_out, int out_size, void* d_ws, size_t ws_size,
                              hipStream_t stream) {
    const float* in  = (const float*)d_in[0];
    const float* wts = (const float*)d_in[1];
    float* out = (float*)d_out;
    float* ws = (float*)d_ws;

    float* colsum   = ws;                    // 65536 (zeroed each call)
    float* rowpartY = ws + 65536;            // 32*65536 = 2097152
    float* row_pool = ws + 2162688;          // 65536
    float* col_pool = ws + 2228224;          // 65536
    float* diagbuf  = ws + 2293760;          // 65536
    float* allpart  = ws + 2359296;          // 4096
    float* diagpart = ws + 2363392;          // 16384
    float* all_sum  = ws + 2379776;          // 64
    float* diag_sum = ws + 2379840;          // 64
    float* Ab       = ws + 2379904;          // 65536
    float* Bb       = ws + 2445440;          // 65536
    float* Dgb      = ws + 2510976;          // 65536
    unsigned short* w0t = (unsigned short*)(ws + 2576512);  // 4096 u16
    unsigned short* w1t = w0t + 4096;                       // 4096 u16

    hipMemsetAsync((void*)colsum, 0, 65536 * sizeof(float), stream);

    sweep_kernel<<<dim3(64, 8), 256, 0, stream>>>(in, rowpartY, colsum);
    rowfin_kernel<<<256, 256, 0, stream>>>(rowpartY, colsum, row_pool, col_pool);
    allpart_kernel<<<64, 256, 0, stream>>>(colsum, allpart);
    diag_kernel<<<256, 256, 0, stream>>>(in, diagbuf, diagpart);
    finB_kernel<<<1, 256, 0, stream>>>(allpart, diagpart, all_sum, diag_sum);
    wconv_kernel<<<16, 256, 0, stream>>>(wts, w0t, w1t);
    abd_kernel<<<1024, 64, 0, stream>>>(wts, col_pool, row_pool, diagbuf,
                                        all_sum, diag_sum, Ab, Bb, Dgb);
    main_kernel<<<2080, 512, 0, stream>>>(in, w0t, w1t, Ab, Bb, Dgb, out);
}

// Round 4
// 314.213 us; speedup vs baseline: 1.4002x; 1.4002x over previous
//
#include <hip/hip_runtime.h>

typedef __attribute__((ext_vector_type(8))) short short8;
typedef __attribute__((ext_vector_type(4))) float floatx4;

__device__ __forceinline__ unsigned short f2bf(float f) {
    unsigned u = __float_as_uint(f);
    unsigned r = (u + 0x7fffu + ((u >> 16) & 1u)) >> 16;
    return (unsigned short)r;
}

__device__ __forceinline__ short8 cvt8(const float* p) {
    floatx4 a = *(const floatx4*)p;
    floatx4 b = *(const floatx4*)(p + 4);
    short8 v;
    v[0] = (short)f2bf(a[0]); v[1] = (short)f2bf(a[1]);
    v[2] = (short)f2bf(a[2]); v[3] = (short)f2bf(a[3]);
    v[4] = (short)f2bf(b[0]); v[5] = (short)f2bf(b[1]);
    v[6] = (short)f2bf(b[2]); v[7] = (short)f2bf(b[3]);
    return v;
}

// =============== pass A: col_pool[r][k] = mean_c in[r][c][k]  (+ diag copy)
// 1024 blocks (one per r), 256 thr, contiguous 256 KB per block, 1 float4 acc
__global__ __launch_bounds__(256) void passA_kernel(const float* __restrict__ in,
        float* __restrict__ col_pool, float* __restrict__ diagbuf) {
    __shared__ float red[16][64];
    int t = threadIdx.x;
    int kq = t & 15;            // float4 index within k
    int cq = t >> 4;            // 16 c-phases
    int r = blockIdx.x;
    const float* base = in + ((size_t)r << 16) + cq * 64 + kq * 4;
    floatx4 acc = (floatx4){0.f, 0.f, 0.f, 0.f};
    #pragma unroll 8
    for (int i = 0; i < 64; ++i)
        acc += *(const floatx4*)(base + i * 1024);    // c = cq + 16*i
    *(floatx4*)&red[cq][kq * 4] = acc;
    __syncthreads();
    if (t < 64) {
        float s = 0.f;
        #pragma unroll
        for (int q = 0; q < 16; ++q) s += red[q][t];
        col_pool[r * 64 + t] = s * (1.f / 1024.f);
        diagbuf[r * 64 + t] = in[((size_t)r << 16) + r * 64 + t];
    }
}

// =============== pass B: row-sum partials. grid (64, 8), 256 thr, 1 float4 acc
__global__ __launch_bounds__(256) void passB_kernel(const float* __restrict__ in,
        float* __restrict__ rowpartY) {
    const floatx4* in4 = (const floatx4*)in;
    int j = blockIdx.x * 256 + threadIdx.x;          // float4 slot in [0,16384)
    int r0 = blockIdx.y * 128;
    floatx4 acc = (floatx4){0.f, 0.f, 0.f, 0.f};
    #pragma unroll 8
    for (int r = 0; r < 128; ++r)
        acc += in4[(size_t)(r0 + r) * 16384 + j];
    *(floatx4*)&rowpartY[((size_t)blockIdx.y * 16384 + j) * 4] = acc;
}

// =============== rowfin: reduce 8 partials -> row_pool
__global__ __launch_bounds__(256) void rowfin_kernel(const float* __restrict__ rowpartY,
        float* __restrict__ row_pool) {
    int j = blockIdx.x * 256 + threadIdx.x;          // float4 slot
    const floatx4* rp4 = (const floatx4*)rowpartY;
    floatx4 s = (floatx4){0.f, 0.f, 0.f, 0.f};
    #pragma unroll
    for (int y = 0; y < 8; ++y) s += rp4[(size_t)y * 16384 + j];
    s *= (1.f / 1024.f);
    *(floatx4*)&row_pool[j * 4] = s;
}

// =============== finB: all_sum (raw), diag_sum (raw) from col_pool/diagbuf
__global__ __launch_bounds__(256) void finB_kernel(const float* __restrict__ col_pool,
        const float* __restrict__ diagbuf, float* __restrict__ all_sum,
        float* __restrict__ diag_sum) {
    int t = threadIdx.x, k = t & 63, rg = t >> 6;
    float sa = 0.f, sd = 0.f;
    #pragma unroll 8
    for (int r = rg; r < 1024; r += 4) {
        sa += col_pool[r * 64 + k];
        sd += diagbuf[r * 64 + k];
    }
    __shared__ float red[2][4][64];
    red[0][rg][k] = sa;
    red[1][rg][k] = sd;
    __syncthreads();
    if (t < 64) {
        // col_pool rows are means: sum_r col_pool[r][k] = all_raw/1024
        all_sum[t]  = (red[0][0][t] + red[0][1][t] + red[0][2][t] + red[0][3][t]) * 1024.f;
        diag_sum[t] =  red[1][0][t] + red[1][1][t] + red[1][2][t] + red[1][3][t];
    }
}

// =============== W0/W1 transposed -> bf16 bits
__global__ __launch_bounds__(256) void wconv_kernel(const float* __restrict__ wts,
        unsigned short* __restrict__ w0t, unsigned short* __restrict__ w1t) {
    int idx = blockIdx.x * 256 + threadIdx.x;
    int n = idx >> 6, k = idx & 63;
    w0t[idx] = f2bf(wts[k * 64 + n]);
    w1t[idx] = f2bf(wts[4096 + k * 64 + n]);
}

// =============== A[c], B[r], Dg[i] tables (fp32)
__global__ __launch_bounds__(64) void abd_kernel(const float* __restrict__ W,
        const float* __restrict__ col_pool, const float* __restrict__ row_pool,
        const float* __restrict__ diagbuf, const float* __restrict__ all_sum,
        const float* __restrict__ diag_sum,
        float* __restrict__ Ab, float* __restrict__ Bb, float* __restrict__ Dgb) {
    __shared__ float rp[64], cp[64], dv[64], ap[64], dp[64];
    int i = blockIdx.x, o = threadIdx.x;
    rp[o] = row_pool[i * 64 + o];
    cp[o] = col_pool[i * 64 + o];
    dv[o] = diagbuf[i * 64 + o];
    ap[o] = all_sum[o] * (1.f / 1048576.f);
    dp[o] = diag_sum[o] * (1.f / 1024.f);
    __syncthreads();
    float aA = 0.f, aB = 0.f, aD = 0.f;
    #pragma unroll 4
    for (int k = 0; k < 64; ++k) {
        int ko = k * 64 + o;
        aA += rp[k] * W[3 * 4096 + ko] + cp[k] * W[6 * 4096 + ko]
            + dv[k] * W[13 * 4096 + ko] + ap[k] * W[7 * 4096 + ko]
            + dp[k] * W[12 * 4096 + ko];
        aB += rp[k] * W[4 * 4096 + ko] + cp[k] * W[5 * 4096 + ko]
            + dv[k] * W[14 * 4096 + ko];
        aD += dv[k] * W[2 * 4096 + ko] + rp[k] * W[10 * 4096 + ko]
            + cp[k] * W[11 * 4096 + ko] + dp[k] * W[8 * 4096 + ko]
            + ap[k] * W[9 * 4096 + ko];
    }
    Ab[i * 64 + o] = aA;
    Bb[i * 64 + o] = aB;
    Dgb[i * 64 + o] = aD;
}

// =============== main paired-tile kernel: 2080 blocks x 512 thr
__global__ __launch_bounds__(512) void main_kernel(const float* __restrict__ in,
        const unsigned short* __restrict__ w0t, const unsigned short* __restrict__ w1t,
        const float* __restrict__ Ab, const float* __restrict__ Bb,
        const float* __restrict__ Dgb, float* __restrict__ out) {
    __shared__ short lds[32768];          // 2 tiles * 256 rows * 64 bf16 (swizzled)

    int t = threadIdx.x;
    int lane = t & 63, w = t >> 6;        // 8 waves
    int lrow = lane & 15, lhi = lane >> 4;

    // triangular decode
    int p = blockIdx.x;
    float fb = (129.0f - sqrtf(129.0f * 129.0f - 8.0f * (float)p)) * 0.5f;
    int bi = (int)fb;
    while (bi > 0 && bi * (129 - bi) / 2 > p) --bi;
    while ((bi + 1) * (129 - (bi + 1)) / 2 <= p) ++bi;
    int bj = bi + (p - bi * (129 - bi) / 2);
    int r0 = bi * 16, c0 = bj * 16;

    // W fragments (register-resident)
    short8 bw0[2][4], bw1[2][4];
    #pragma unroll
    for (int kg = 0; kg < 2; ++kg)
        #pragma unroll
        for (int nt = 0; nt < 4; ++nt) {
            int off = (nt * 16 + lrow) * 64 + kg * 32 + lhi * 8;
            bw0[kg][nt] = *(const short8*)(w0t + off);
            bw1[kg][nt] = *(const short8*)(w1t + off);
        }

    // stage both tiles: thread t -> (sj, sg), i = 4q + (t>>7)
    int sj = (t & 127) >> 3;
    int sg = t & 7;
    int shalf = t >> 7;                   // 0..3
    #pragma unroll
    for (int sel = 0; sel < 2; ++sel) {
        int R = sel ? c0 : r0;
        int C = sel ? r0 : c0;
        #pragma unroll
        for (int q = 0; q < 4; ++q) {
            int i = 4 * q + shalf;
            const float* src = in + (((size_t)(R + i) << 10) + (C + sj)) * 64 + sg * 8;
            short8 v = cvt8(src);
            int row = i * 16 + sj;
            int wg = sg ^ ((row ^ (row >> 4)) & 7);
            *(short8*)(lds + sel * 16384 + row * 64 + wg * 8) = v;
        }
    }
    __syncthreads();

    // compute: wave w does I = 2w, 2w+1 of each out-tile
    #pragma unroll
    for (int sel = 0; sel < 2; ++sel) {
        if (sel == 1 && bi == bj) continue;   // diagonal pair: both tiles identical
        int selb = sel * 16384;
        int othb = (sel ^ 1) * 16384;
        int rbase = sel ? c0 : r0;
        int cbase = sel ? r0 : c0;
        #pragma unroll
        for (int mf = 0; mf < 2; ++mf) {
            int I = w * 2 + mf;
            int mrow = I * 16 + lrow;
            int swzm = (mrow ^ (mrow >> 4)) & 7;
            int trow = lrow * 16 + I;
            int swzt = (trow ^ (trow >> 4)) & 7;
            short8 ad[2], at2[2];
            #pragma unroll
            for (int kg = 0; kg < 2; ++kg) {
                ad[kg]  = *(const short8*)(lds + selb + mrow * 64 + ((kg * 4 + lhi) ^ swzm) * 8);
                at2[kg] = *(const short8*)(lds + othb + trow * 64 + ((kg * 4 + lhi) ^ swzt) * 8);
            }
            floatx4 acc[4];
            #pragma unroll
            for (int nt = 0; nt < 4; ++nt) acc[nt] = (floatx4){0.f, 0.f, 0.f, 0.f};
            #pragma unroll
            for (int nt = 0; nt < 4; ++nt) {
                acc[nt] = __builtin_amdgcn_mfma_f32_16x16x32_bf16(ad[0],  bw0[0][nt], acc[nt], 0, 0, 0);
                acc[nt] = __builtin_amdgcn_mfma_f32_16x16x32_bf16(ad[1],  bw0[1][nt], acc[nt], 0, 0, 0);
                acc[nt] = __builtin_amdgcn_mfma_f32_16x16x32_bf16(at2[0], bw1[0][nt], acc[nt], 0, 0, 0);
                acc[nt] = __builtin_amdgcn_mfma_f32_16x16x32_bf16(at2[1], bw1[1][nt], acc[nt], 0, 0, 0);
            }
            int ridx = rbase + I;
            float br[4];
            #pragma unroll
            for (int nt = 0; nt < 4; ++nt) br[nt] = Bb[ridx * 64 + nt * 16 + lrow];
            #pragma unroll
            for (int jj = 0; jj < 4; ++jj) {
                int j = lhi * 4 + jj;
                int cidx = cbase + j;
                size_t s = ((size_t)ridx << 10) + cidx;
                bool isd = (ridx == cidx);
                #pragma unroll
                for (int nt = 0; nt < 4; ++nt) {
                    int n = nt * 16 + lrow;
                    float v = acc[nt][jj] + Ab[cidx * 64 + n] + br[nt];
                    if (isd) v += Dgb[ridx * 64 + n];
                    out[s * 64 + n] = v;
                }
            }
        }
    }
}

extern "C" void kernel_launch(void* const* d_in, const int* in_sizes, int n_in,
                              void* d_out, int out_size, void* d_ws, size_t ws_size,
                              hipStream_t stream) {
    const float* in  = (const float*)d_in[0];
    const float* wts = (const float*)d_in[1];
    float* out = (float*)d_out;
    float* ws = (float*)d_ws;

    float* col_pool = ws;                    // 65536
    float* diagbuf  = ws + 65536;            // 65536
    float* rowpartY = ws + 131072;           // 8*65536 = 524288
    float* row_pool = ws + 655360;           // 65536
    float* all_sum  = ws + 720896;           // 64
    float* diag_sum = ws + 720960;           // 64
    float* Ab       = ws + 721024;           // 65536
    float* Bb       = ws + 786560;           // 65536
    float* Dgb      = ws + 852096;           // 65536
    unsigned short* w0t = (unsigned short*)(ws + 917632);  // 4096 u16
    unsigned short* w1t = w0t + 4096;                      // 4096 u16

    passA_kernel<<<1024, 256, 0, stream>>>(in, col_pool, diagbuf);
    passB_kernel<<<dim3(64, 8), 256, 0, stream>>>(in, rowpartY);
    rowfin_kernel<<<64, 256, 0, stream>>>(rowpartY, row_pool);
    finB_kernel<<<1, 256, 0, stream>>>(col_pool, diagbuf, all_sum, diag_sum);
    wconv_kernel<<<16, 256, 0, stream>>>(wts, w0t, w1t);
    abd_kernel<<<1024, 64, 0, stream>>>(wts, col_pool, row_pool, diagbuf,
                                        all_sum, diag_sum, Ab, Bb, Dgb);
    main_kernel<<<2080, 512, 0, stream>>>(in, w0t, w1t, Ab, Bb, Dgb, out);
}

// Round 5
// 254.184 us; speedup vs baseline: 1.7308x; 1.2362x over previous
//
#include <hip/hip_runtime.h>
#include <hip/hip_bf16.h>

typedef __attribute__((ext_vector_type(8))) short short8;
typedef __attribute__((ext_vector_type(4))) float floatx4;

__device__ __forceinline__ unsigned short f2bf(float f) {
    __hip_bfloat16 h = __float2bfloat16(f);      // RNE; compiler can fuse to v_cvt_pk_bf16_f32
    return __builtin_bit_cast(unsigned short, h);
}

__device__ __forceinline__ short8 cvt8(const float* p) {
    floatx4 a = *(const floatx4*)p;
    floatx4 b = *(const floatx4*)(p + 4);
    short8 v;
    v[0] = (short)f2bf(a[0]); v[1] = (short)f2bf(a[1]);
    v[2] = (short)f2bf(a[2]); v[3] = (short)f2bf(a[3]);
    v[4] = (short)f2bf(b[0]); v[5] = (short)f2bf(b[1]);
    v[6] = (short)f2bf(b[2]); v[7] = (short)f2bf(b[3]);
    return v;
}

// =============== fused single-read sweep: block = 64 rows x 16 cols
// grid (64 cb, 16 rb), 256 thr. Produces colpart[cb][1024r][64k], rowpart[rb][1024c][64k]
__global__ __launch_bounds__(256) void sweep_kernel(const float* __restrict__ in,
        float* __restrict__ rowpart, float* __restrict__ colpart) {
    __shared__ float col_lds[64][64];     // [r_loc][k] col partial (sum over block's 16 c)
    __shared__ float rowp[4][16][64];     // [wave][c_loc][k] row partial
    int t = threadIdx.x;
    int lane = t & 63, w = t >> 6;
    int kq = lane & 15, cg = lane >> 4;
    int c0 = blockIdx.x * 16;
    int r0 = blockIdx.y * 64;

    floatx4 rowacc[4];
    #pragma unroll
    for (int cl = 0; cl < 4; ++cl) rowacc[cl] = (floatx4){0.f, 0.f, 0.f, 0.f};

    #pragma unroll 4
    for (int i = 0; i < 16; ++i) {
        int rloc = w + 4 * i;
        const float* p = in + ((size_t)(r0 + rloc) << 16) + (size_t)c0 * 64 + cg * 64 + kq * 4;
        floatx4 v0 = *(const floatx4*)(p);          // c = cg
        floatx4 v1 = *(const floatx4*)(p + 256);    // c = cg+4
        floatx4 v2 = *(const floatx4*)(p + 512);    // c = cg+8
        floatx4 v3 = *(const floatx4*)(p + 768);    // c = cg+12
        rowacc[0] += v0; rowacc[1] += v1; rowacc[2] += v2; rowacc[3] += v3;
        floatx4 cs = v0 + v1 + v2 + v3;
        #pragma unroll
        for (int m = 16; m <= 32; m <<= 1) {
            cs[0] += __shfl_xor(cs[0], m);
            cs[1] += __shfl_xor(cs[1], m);
            cs[2] += __shfl_xor(cs[2], m);
            cs[3] += __shfl_xor(cs[3], m);
        }
        if (cg == 0) *(floatx4*)&col_lds[rloc][kq * 4] = cs;
    }
    #pragma unroll
    for (int cl = 0; cl < 4; ++cl)
        *(floatx4*)&rowp[w][cg + 4 * cl][kq * 4] = rowacc[cl];
    __syncthreads();

    // write col partials: 4096 floats -> colpart[cb][r0+rloc][k]
    #pragma unroll
    for (int q = 0; q < 4; ++q) {
        int idx = q * 256 + t;
        int rloc = idx >> 4, kq2 = idx & 15;
        floatx4 v = *(const floatx4*)&col_lds[rloc][kq2 * 4];
        *(floatx4*)&colpart[(size_t)blockIdx.x * 65536 + (size_t)(r0 + rloc) * 64 + kq2 * 4] = v;
    }
    // reduce row partials over 4 waves: thread t -> (c = t>>4, kq2 = t&15)
    {
        int c = t >> 4, kq2 = t & 15;
        floatx4 s = *(const floatx4*)&rowp[0][c][kq2 * 4];
        s += *(const floatx4*)&rowp[1][c][kq2 * 4];
        s += *(const floatx4*)&rowp[2][c][kq2 * 4];
        s += *(const floatx4*)&rowp[3][c][kq2 * 4];
        *(floatx4*)&rowpart[(size_t)blockIdx.y * 65536 + (size_t)(c0 + c) * 64 + kq2 * 4] = s;
    }
}

// =============== rowfin: reduce 16 row partials -> row_pool (mean)
__global__ __launch_bounds__(256) void rowfin_kernel(const float* __restrict__ rowpart,
        float* __restrict__ row_pool) {
    int j = blockIdx.x * 256 + threadIdx.x;          // float4 slot
    const floatx4* rp4 = (const floatx4*)rowpart;
    floatx4 s = (floatx4){0.f, 0.f, 0.f, 0.f};
    #pragma unroll
    for (int y = 0; y < 16; ++y) s += rp4[(size_t)y * 16384 + j];
    s *= (1.f / 1024.f);
    *(floatx4*)&row_pool[j * 4] = s;
}

// =============== colfin: reduce 64 col partials -> col_pool (mean)
__global__ __launch_bounds__(256) void colfin_kernel(const float* __restrict__ colpart,
        float* __restrict__ col_pool) {
    int j = blockIdx.x * 256 + threadIdx.x;          // float4 slot
    const floatx4* cp4 = (const floatx4*)colpart;
    floatx4 s = (floatx4){0.f, 0.f, 0.f, 0.f};
    #pragma unroll 8
    for (int y = 0; y < 64; ++y) s += cp4[(size_t)y * 16384 + j];
    s *= (1.f / 1024.f);
    *(floatx4*)&col_pool[j * 4] = s;
}

// =============== diag extraction (256 blocks x 4 i)
__global__ __launch_bounds__(256) void diag_kernel(const float* __restrict__ in,
        float* __restrict__ diagbuf) {
    int t = threadIdx.x, k = t & 63, il = t >> 6;
    int i = blockIdx.x * 4 + il;
    diagbuf[i * 64 + k] = in[(size_t)i * 65600 + k];   // (i*1024+i)*64
}

// =============== finB: all_sum (raw), diag_sum (raw)
__global__ __launch_bounds__(256) void finB_kernel(const float* __restrict__ col_pool,
        const float* __restrict__ diagbuf, float* __restrict__ all_sum,
        float* __restrict__ diag_sum) {
    __shared__ float red[2][16][64];
    int t = threadIdx.x, kq = t & 15, rg = t >> 4;
    const floatx4* cp4 = (const floatx4*)col_pool;
    const floatx4* db4 = (const floatx4*)diagbuf;
    floatx4 sa = (floatx4){0.f, 0.f, 0.f, 0.f};
    floatx4 sd = (floatx4){0.f, 0.f, 0.f, 0.f};
    #pragma unroll 4
    for (int r = rg; r < 1024; r += 16) {
        sa += cp4[r * 16 + kq];
        sd += db4[r * 16 + kq];
    }
    *(floatx4*)&red[0][rg][kq * 4] = sa;
    *(floatx4*)&red[1][rg][kq * 4] = sd;
    __syncthreads();
    if (t < 64) {
        float a = 0.f, d = 0.f;
        #pragma unroll
        for (int q = 0; q < 16; ++q) { a += red[0][q][t]; d += red[1][q][t]; }
        all_sum[t]  = a * 1024.f;     // col_pool rows are means over 1024
        diag_sum[t] = d;
    }
}

// =============== W0/W1 transposed -> bf16 bits
__global__ __launch_bounds__(256) void wconv_kernel(const float* __restrict__ wts,
        unsigned short* __restrict__ w0t, unsigned short* __restrict__ w1t) {
    int idx = blockIdx.x * 256 + threadIdx.x;
    int n = idx >> 6, k = idx & 63;
    w0t[idx] = f2bf(wts[k * 64 + n]);
    w1t[idx] = f2bf(wts[4096 + k * 64 + n]);
}

// =============== A[c], B[r], Dg[i] tables (fp32)
__global__ __launch_bounds__(64) void abd_kernel(const float* __restrict__ W,
        const float* __restrict__ col_pool, const float* __restrict__ row_pool,
        const float* __restrict__ diagbuf, const float* __restrict__ all_sum,
        const float* __restrict__ diag_sum,
        float* __restrict__ Ab, float* __restrict__ Bb, float* __restrict__ Dgb) {
    __shared__ float rp[64], cp[64], dv[64], ap[64], dp[64];
    int i = blockIdx.x, o = threadIdx.x;
    rp[o] = row_pool[i * 64 + o];
    cp[o] = col_pool[i * 64 + o];
    dv[o] = diagbuf[i * 64 + o];
    ap[o] = all_sum[o] * (1.f / 1048576.f);
    dp[o] = diag_sum[o] * (1.f / 1024.f);
    __syncthreads();
    float aA = 0.f, aB = 0.f, aD = 0.f;
    #pragma unroll 4
    for (int k = 0; k < 64; ++k) {
        int ko = k * 64 + o;
        aA += rp[k] * W[3 * 4096 + ko] + cp[k] * W[6 * 4096 + ko]
            + dv[k] * W[13 * 4096 + ko] + ap[k] * W[7 * 4096 + ko]
            + dp[k] * W[12 * 4096 + ko];
        aB += rp[k] * W[4 * 4096 + ko] + cp[k] * W[5 * 4096 + ko]
            + dv[k] * W[14 * 4096 + ko];
        aD += dv[k] * W[2 * 4096 + ko] + rp[k] * W[10 * 4096 + ko]
            + cp[k] * W[11 * 4096 + ko] + dp[k] * W[8 * 4096 + ko]
            + ap[k] * W[9 * 4096 + ko];
    }
    Ab[i * 64 + o] = aA;
    Bb[i * 64 + o] = aB;
    Dgb[i * 64 + o] = aD;
}

// =============== main paired-tile kernel: 2080 blocks x 256 thr
__global__ __launch_bounds__(256) void main_kernel(const float* __restrict__ in,
        const unsigned short* __restrict__ w0t, const unsigned short* __restrict__ w1t,
        const float* __restrict__ Ab, const float* __restrict__ Bb,
        const float* __restrict__ Dgb, float* __restrict__ out) {
    __shared__ short lds[32768];          // 2 tiles * 256 rows * 64 bf16 (swizzled)

    int t = threadIdx.x;
    int lane = t & 63, w = t >> 6;        // 4 waves
    int lrow = lane & 15, lhi = lane >> 4;

    // triangular decode
    int p = blockIdx.x;
    float fb = (129.0f - sqrtf(129.0f * 129.0f - 8.0f * (float)p)) * 0.5f;
    int bi = (int)fb;
    while (bi > 0 && bi * (129 - bi) / 2 > p) --bi;
    while ((bi + 1) * (129 - (bi + 1)) / 2 <= p) ++bi;
    int bj = bi + (p - bi * (129 - bi) / 2);
    int r0 = bi * 16, c0 = bj * 16;

    // W fragments (register-resident)
    short8 bw0[2][4], bw1[2][4];
    #pragma unroll
    for (int kg = 0; kg < 2; ++kg)
        #pragma unroll
        for (int nt = 0; nt < 4; ++nt) {
            int off = (nt * 16 + lrow) * 64 + kg * 32 + lhi * 8;
            bw0[kg][nt] = *(const short8*)(w0t + off);
            bw1[kg][nt] = *(const short8*)(w1t + off);
        }

    // stage both tiles: thread t -> (sj, sg), i = 2q + (t>>7)
    int sj = (t & 127) >> 3;
    int sg = t & 7;
    int shalf = t >> 7;                   // 0..1
    #pragma unroll
    for (int sel = 0; sel < 2; ++sel) {
        int R = sel ? c0 : r0;
        int C = sel ? r0 : c0;
        #pragma unroll
        for (int q = 0; q < 8; ++q) {
            int i = 2 * q + shalf;
            const float* src = in + (((size_t)(R + i) << 10) + (C + sj)) * 64 + sg * 8;
            short8 v = cvt8(src);
            int row = i * 16 + sj;
            int wg = sg ^ ((row ^ (row >> 4)) & 7);
            *(short8*)(lds + sel * 16384 + row * 64 + wg * 8) = v;
        }
    }
    __syncthreads();

    // compute: wave w does I = 4w..4w+3 of each out-tile
    #pragma unroll
    for (int sel = 0; sel < 2; ++sel) {
        if (sel == 1 && bi == bj) continue;   // diagonal pair: tiles identical
        int selb = sel * 16384;
        int othb = (sel ^ 1) * 16384;
        int rbase = sel ? c0 : r0;
        int cbase = sel ? r0 : c0;
        #pragma unroll
        for (int mf = 0; mf < 4; ++mf) {
            int I = w * 4 + mf;
            int mrow = I * 16 + lrow;
            int swzm = (mrow ^ (mrow >> 4)) & 7;
            int trow = lrow * 16 + I;
            int swzt = (trow ^ (trow >> 4)) & 7;
            short8 ad[2], at2[2];
            #pragma unroll
            for (int kg = 0; kg < 2; ++kg) {
                ad[kg]  = *(const short8*)(lds + selb + mrow * 64 + ((kg * 4 + lhi) ^ swzm) * 8);
                at2[kg] = *(const short8*)(lds + othb + trow * 64 + ((kg * 4 + lhi) ^ swzt) * 8);
            }
            floatx4 acc[4];
            #pragma unroll
            for (int nt = 0; nt < 4; ++nt) acc[nt] = (floatx4){0.f, 0.f, 0.f, 0.f};
            #pragma unroll
            for (int nt = 0; nt < 4; ++nt) {
                acc[nt] = __builtin_amdgcn_mfma_f32_16x16x32_bf16(ad[0],  bw0[0][nt], acc[nt], 0, 0, 0);
                acc[nt] = __builtin_amdgcn_mfma_f32_16x16x32_bf16(ad[1],  bw0[1][nt], acc[nt], 0, 0, 0);
                acc[nt] = __builtin_amdgcn_mfma_f32_16x16x32_bf16(at2[0], bw1[0][nt], acc[nt], 0, 0, 0);
                acc[nt] = __builtin_amdgcn_mfma_f32_16x16x32_bf16(at2[1], bw1[1][nt], acc[nt], 0, 0, 0);
            }
            int ridx = rbase + I;
            float br[4];
            #pragma unroll
            for (int nt = 0; nt < 4; ++nt) br[nt] = Bb[ridx * 64 + nt * 16 + lrow];
            #pragma unroll
            for (int jj = 0; jj < 4; ++jj) {
                int j = lhi * 4 + jj;
                int cidx = cbase + j;
                size_t s = ((size_t)ridx << 10) + cidx;
                bool isd = (ridx == cidx);
                #pragma unroll
                for (int nt = 0; nt < 4; ++nt) {
                    int n = nt * 16 + lrow;
                    float v = acc[nt][jj] + Ab[cidx * 64 + n] + br[nt];
                    if (isd) v += Dgb[ridx * 64 + n];
                    out[s * 64 + n] = v;
                }
            }
        }
    }
}

extern "C" void kernel_launch(void* const* d_in, const int* in_sizes, int n_in,
                              void* d_out, int out_size, void* d_ws, size_t ws_size,
                              hipStream_t stream) {
    const float* in  = (const float*)d_in[0];
    const float* wts = (const float*)d_in[1];
    float* out = (float*)d_out;
    float* ws = (float*)d_ws;

    float* colpart  = ws;                    // 64*65536 = 4194304
    float* rowpart  = ws + 4194304;          // 16*65536 = 1048576
    float* row_pool = ws + 5242880;          // 65536
    float* col_pool = ws + 5308416;          // 65536
    float* diagbuf  = ws + 5373952;          // 65536
    float* all_sum  = ws + 5439488;          // 64
    float* diag_sum = ws + 5439552;          // 64
    float* Ab       = ws + 5439616;          // 65536
    float* Bb       = ws + 5505152;          // 65536
    float* Dgb      = ws + 5570688;          // 65536
    unsigned short* w0t = (unsigned short*)(ws + 5636224);  // 4096 u16
    unsigned short* w1t = w0t + 4096;                       // 4096 u16

    sweep_kernel<<<dim3(64, 16), 256, 0, stream>>>(in, rowpart, colpart);
    rowfin_kernel<<<64, 256, 0, stream>>>(rowpart, row_pool);
    colfin_kernel<<<64, 256, 0, stream>>>(colpart, col_pool);
    diag_kernel<<<256, 256, 0, stream>>>(in, diagbuf);
    finB_kernel<<<1, 256, 0, stream>>>(col_pool, diagbuf, all_sum, diag_sum);
    wconv_kernel<<<16, 256, 0, stream>>>(wts, w0t, w1t);
    abd_kernel<<<1024, 64, 0, stream>>>(wts, col_pool, row_pool, diagbuf,
                                        all_sum, diag_sum, Ab, Bb, Dgb);
    main_kernel<<<2080, 256, 0, stream>>>(in, w0t, w1t, Ab, Bb, Dgb, out);
}